// Round 1
// baseline (304.258 us; speedup 1.0000x reference)
//
#include <hip/hip_runtime.h>
#include <cstdint>
#include <cstddef>

// Squared euclidean distance: dist[m][n] = ||a_m||^2 + ||b_n||^2 - 2 a_m.b_n
// M=100000, N=2048, K=64. f32 in/out. Cross term via bf16 MFMA 16x16x32.

typedef __bf16 v8bf __attribute__((ext_vector_type(8)));
typedef float  v4f  __attribute__((ext_vector_type(4)));

__device__ inline unsigned short f32_to_bf16_rne(float f) {
    union { float f; uint32_t u; } c; c.f = f;
    uint32_t u = c.u;
    // round-to-nearest-even truncation to bf16 (inputs are normal gaussians)
    uint32_t r = (u + 0x7fffu + ((u >> 16) & 1u)) >> 16;
    return (unsigned short)r;
}

// Convert mat_2 (N x 64 f32) -> bf16 in ws, and compute sq2[n] = ||b_n||^2 (f32).
__global__ __launch_bounds__(256) void prep_kernel(const float* __restrict__ B,
                                                   unsigned short* __restrict__ Bbf,
                                                   float* __restrict__ sq2, int N) {
    int t = blockIdx.x * 256 + threadIdx.x;   // 4 threads per row, 16 elems each
    int row = t >> 2;
    if (row >= N) return;
    int q = (t & 3) * 16;
    const float* src = B + (size_t)row * 64 + q;
    unsigned short* dst = Bbf + (size_t)row * 64 + q;
    float s = 0.f;
#pragma unroll
    for (int i = 0; i < 4; ++i) {
        float4 v = *reinterpret_cast<const float4*>(src + 4 * i);
        s += v.x * v.x + v.y * v.y + v.z * v.z + v.w * v.w;
        uint2 p;
        p.x = (uint32_t)f32_to_bf16_rne(v.x) | ((uint32_t)f32_to_bf16_rne(v.y) << 16);
        p.y = (uint32_t)f32_to_bf16_rne(v.z) | ((uint32_t)f32_to_bf16_rne(v.w) << 16);
        *reinterpret_cast<uint2*>(dst + 4 * i) = p;
    }
    s += __shfl_xor(s, 1);
    s += __shfl_xor(s, 2);
    if ((t & 3) == 0) sq2[row] = s;
}

// Block: 256 threads = 4 waves (2x2). Block tile: 64 rows x full N (chunks of 128).
// Wave tile per chunk: 32 rows x 64 cols = 2x4 MFMA 16x16 tiles, K=64 = 2 k-steps.
__global__ __launch_bounds__(256) void dist_kernel(const float* __restrict__ A,
                                                   const unsigned short* __restrict__ Bbf,
                                                   const float* __restrict__ sq2,
                                                   float* __restrict__ out,
                                                   int M, int N) {
    __shared__ alignas(16) unsigned short a_lds[64][64];  // 8 KB bf16 A tile
    __shared__ float sq1_lds[64];

    const int t  = threadIdx.x;
    const int m0 = blockIdx.x * 64;

    // ---- stage A tile (f32 -> bf16) + row norms ----
    {
        int r = t >> 2;
        int q = (t & 3) * 16;
        int m = m0 + r; if (m > M - 1) m = M - 1;   // clamp tail rows (stores predicated later)
        const float* src = A + (size_t)m * 64 + q;
        float s = 0.f;
#pragma unroll
        for (int i = 0; i < 4; ++i) {
            float4 v = *reinterpret_cast<const float4*>(src + 4 * i);
            s += v.x * v.x + v.y * v.y + v.z * v.z + v.w * v.w;
            uint2 p;
            p.x = (uint32_t)f32_to_bf16_rne(v.x) | ((uint32_t)f32_to_bf16_rne(v.y) << 16);
            p.y = (uint32_t)f32_to_bf16_rne(v.z) | ((uint32_t)f32_to_bf16_rne(v.w) << 16);
            *reinterpret_cast<uint2*>(&a_lds[r][q + 4 * i]) = p;
        }
        s += __shfl_xor(s, 1);
        s += __shfl_xor(s, 2);
        if ((t & 3) == 0) sq1_lds[r] = s;
    }
    __syncthreads();

    const int lane = t & 63;
    const int w    = t >> 6;
    const int wm   = w >> 1;      // 0..1 : row half
    const int wn   = w & 1;       // 0..1 : col half within 128-chunk
    const int lg   = lane >> 4;   // lane group 0..3
    const int li   = lane & 15;

    // A fragments: lane li = row-in-tile, k = 8*lg + e (+32*kb). Held in regs all block.
    v8bf afrag[2][2];
#pragma unroll
    for (int rt = 0; rt < 2; ++rt)
#pragma unroll
        for (int kb = 0; kb < 2; ++kb) {
            int row = 32 * wm + 16 * rt + li;
            int k0  = kb * 32 + 8 * lg;
            afrag[rt][kb] = *reinterpret_cast<const v8bf*>(&a_lds[row][k0]);
        }

    // sq1 for the rows this lane's D-fragment covers: row = 16*rt + 4*lg + j
    float s1[2][4];
#pragma unroll
    for (int rt = 0; rt < 2; ++rt)
#pragma unroll
        for (int j = 0; j < 4; ++j)
            s1[rt][j] = sq1_lds[32 * wm + 16 * rt + 4 * lg + j];

    for (int nc = 0; nc < N; nc += 128) {
        const int ncol = nc + 64 * wn;

        // B fragments straight from global (bf16 in ws, L2-resident)
        v8bf bfrag[4][2];
#pragma unroll
        for (int ct = 0; ct < 4; ++ct)
#pragma unroll
            for (int kb = 0; kb < 2; ++kb) {
                int col = ncol + 16 * ct + li;
                bfrag[ct][kb] = *reinterpret_cast<const v8bf*>(
                    &Bbf[(size_t)col * 64 + kb * 32 + 8 * lg]);
            }

        v4f acc[2][4];
#pragma unroll
        for (int rt = 0; rt < 2; ++rt)
#pragma unroll
            for (int ct = 0; ct < 4; ++ct) {
                v4f z = {0.f, 0.f, 0.f, 0.f};
                acc[rt][ct] = z;
            }

#pragma unroll
        for (int rt = 0; rt < 2; ++rt)
#pragma unroll
            for (int ct = 0; ct < 4; ++ct) {
                acc[rt][ct] = __builtin_amdgcn_mfma_f32_16x16x32_bf16(
                    afrag[rt][0], bfrag[ct][0], acc[rt][ct], 0, 0, 0);
                acc[rt][ct] = __builtin_amdgcn_mfma_f32_16x16x32_bf16(
                    afrag[rt][1], bfrag[ct][1], acc[rt][ct], 0, 0, 0);
            }

        // Epilogue: D mapping col = li, row = 4*lg + j (m89-verified).
#pragma unroll
        for (int rt = 0; rt < 2; ++rt)
#pragma unroll
            for (int ct = 0; ct < 4; ++ct) {
                int col  = ncol + 16 * ct + li;
                float s2 = sq2[col];
#pragma unroll
                for (int j = 0; j < 4; ++j) {
                    int row = m0 + 32 * wm + 16 * rt + 4 * lg + j;
                    if (row < M)
                        out[(size_t)row * N + col] = s1[rt][j] + s2 - 2.0f * acc[rt][ct][j];
                }
            }
    }
}

extern "C" void kernel_launch(void* const* d_in, const int* in_sizes, int n_in,
                              void* d_out, int out_size, void* d_ws, size_t ws_size,
                              hipStream_t stream) {
    const float* A = (const float*)d_in[0];
    const float* B = (const float*)d_in[1];
    const int M = in_sizes[0] / 64;   // 100000
    const int N = in_sizes[1] / 64;   // 2048

    unsigned short* Bbf = (unsigned short*)d_ws;                       // N*64 bf16 = 256 KB
    float* sq2 = (float*)((char*)d_ws + (size_t)N * 64 * sizeof(unsigned short)); // 8 KB
    float* out = (float*)d_out;

    const int prep_threads = N * 4;
    prep_kernel<<<(prep_threads + 255) / 256, 256, 0, stream>>>(B, Bbf, sq2, N);

    const int gridM = (M + 63) / 64;
    dist_kernel<<<gridM, 256, 0, stream>>>(A, Bbf, sq2, out, M, N);
}